// Round 5
// baseline (465.867 us; speedup 1.0000x reference)
//
#include <hip/hip_runtime.h>

// Fully-fused PINN-LISTA, transposed-MFMA + prep prefold + 2-wave H-split.
// Block = 128 threads = 2 waves sharing one 16-sample tile. Wave w owns
// output chunks mt in {2w, 2w+1} (half the H dim): 8 MFMAs + 8-elem tanh
// chain per step instead of 16 -> grid 2048 blocks now puts 4 waves/SIMD
// (was 2) for latency hiding. Cross-wave exchange per step: variance
// partial (parity-buffered) + 2 h B-fragments (8B/lane, conflict-free),
// 2 barriers/step. ISTA same split, 1 barrier/iter (parity-buffered).

#define NB 32768
#define WIN 100
#define HH 64
#define AA 64
#define KITER 8
#define NAPPC 4
#define DTC 0.1f
#define LNEPS 1e-5f
#define K2E 2.8853900817779268f  // 2*log2(e)

// d_ws byte offsets
#define WS_WREC 0        // f16 [4][4][64][4]   = 8192 B   (A-frag order, [mt*4+kt][lane][4])
#define WS_WE   8192     // f16 [8][64][112]    = 114688 B (K padded 100->112, zeros)
#define WS_WR   122880   // f16 [8][64][64]     = 65536 B
#define WS_WC   188416   // f32 [64]
#define WS_BC   188672   // f32 [64]
#define WS_DEC  188928   // f32 [64]
#define WS_LAM  189184   // f32 [8][64] -> ends 191232

typedef _Float16 f16x4 __attribute__((ext_vector_type(4)));
typedef __fp16 fp16x2 __attribute__((ext_vector_type(2)));
typedef float f32x4 __attribute__((ext_vector_type(4)));

union H4 { f16x4 v; fp16x2 h[2]; };

__device__ __forceinline__ float exp2_fast(float x) { return __builtin_amdgcn_exp2f(x); }
__device__ __forceinline__ float rcp_fast(float x) { return __builtin_amdgcn_rcpf(x); }
__device__ __forceinline__ float rsq_fast(float x) { return __builtin_amdgcn_rsqf(x); }
__device__ __forceinline__ float log2_fast(float x) { return __builtin_amdgcn_logf(x); }
__device__ __forceinline__ float med3(float x, float lo, float hi) {
  return __builtin_amdgcn_fmed3f(x, lo, hi);
}
__device__ __forceinline__ float softplus_fast(float x) {
  float ax = fabsf(x);
  float e = exp2_fast(-ax * 1.4426950408889634f);
  return fmaxf(x, 0.0f) + log2_fast(1.0f + e) * 0.6931471805599453f;
}
__device__ __forceinline__ f16x4 pack4(float a, float b, float c2, float d) {
  H4 t;
  t.h[0] = __builtin_amdgcn_cvt_pkrtz(a, b);
  t.h[1] = __builtin_amdgcn_cvt_pkrtz(c2, d);
  return t.v;
}

// ======================= prep kernel =======================
__global__ __launch_bounds__(256) void pinn_prep(
    const float* __restrict__ W_rec, const float* __restrict__ w_in,
    const float* __restrict__ b_in, const float* __restrict__ tau,
    const float* __restrict__ thr, const float* __restrict__ We,
    const float* __restrict__ Wr, char* __restrict__ ws) {
  _Float16* wrec16 = (_Float16*)(ws + WS_WREC);
  _Float16* we16 = (_Float16*)(ws + WS_WE);
  _Float16* wr16 = (_Float16*)(ws + WS_WR);
  float* wc = (float*)(ws + WS_WC);
  float* bc = (float*)(ws + WS_BC);
  float* dec = (float*)(ws + WS_DEC);
  float* lam = (float*)(ws + WS_LAM);
  const int tid = threadIdx.x, bid = blockIdx.x;
  if (bid == 0) {
    __shared__ float rm[64];
    if (tid < 64) {
      float s = 0.f;
      for (int m = 0; m < 64; ++m) s += W_rec[tid * 64 + m];
      rm[tid] = s * (1.f / 64.f);
    }
    __syncthreads();
    for (int idx = tid; idx < 4096; idx += 256) {
      const int j = idx & 3, l = (idx >> 2) & 63, kt = (idx >> 8) & 3, mt = idx >> 10;
      const int k_in = kt * 16 + ((l >> 4) << 2) + j, m = mt * 16 + (l & 15);
      wrec16[idx] = (_Float16)(W_rec[k_in * 64 + m] - rm[k_in]);
    }
    if (tid < 64) {
      float sw = 0.f, sb = 0.f;
      for (int i = 0; i < 64; ++i) { sw += w_in[i]; sb += b_in[i]; }
      wc[tid] = w_in[tid] - sw * (1.f / 64.f);
      bc[tid] = b_in[tid] - sb * (1.f / 64.f);
      dec[tid] = 1.f - DTC / softplus_fast(tau[tid]);
    }
    for (int i = tid; i < 512; i += 256) lam[i] = softplus_fast(thr[i]);
  } else {
    const int stride = (gridDim.x - 1) * 256;
    for (int i = (bid - 1) * 256 + tid; i < 57344 + 32768; i += stride) {
      if (i < 57344) {
        const int row = i / 112, t = i - row * 112;
        we16[i] = (t < WIN) ? (_Float16)We[row * WIN + t] : (_Float16)0.f;
      } else {
        const int j = i - 57344;
        wr16[j] = (_Float16)Wr[j];
      }
    }
  }
}

// ======================= main kernel =======================
__global__ __launch_bounds__(128, 4) void pinn_fused(
    const float* __restrict__ y, const float* __restrict__ ln_w,
    const float* __restrict__ ln_b, const float* __restrict__ Wx0,
    const float* __restrict__ bx0, const float* __restrict__ be,
    const float* __restrict__ head_W, const float* __restrict__ head_b,
    const char* __restrict__ ws, float* __restrict__ out) {
  __shared__ float ybuf[16][101];  // column reads: (c*101)%32 distinct -> conflict-free
  __shared__ __align__(16) _Float16 hx[2][2][2][64][4];  // [parity][wave][mtl][lane][4]
  __shared__ float qx[2][2][64];                          // [parity][wave][lane]
  __shared__ float px[2][4][16];                          // [wave][p][c] head partials

  const _Float16* wrec16 = (const _Float16*)(ws + WS_WREC);
  const _Float16* we16 = (const _Float16*)(ws + WS_WE);
  const _Float16* wr16 = (const _Float16*)(ws + WS_WR);
  const float* wcp = (const float*)(ws + WS_WC);
  const float* bcp = (const float*)(ws + WS_BC);
  const float* decp = (const float*)(ws + WS_DEC);
  const float* lamp = (const float*)(ws + WS_LAM);

  const int tid = threadIdx.x;
  const int w = tid >> 6;      // wave id: owns mt = 2w, 2w+1
  const int l = tid & 63;
  const int c = l & 15;        // sample (C col / B col / A row)
  const int g = l >> 4;        // lane group
  const int s0 = blockIdx.x * 16;

  // ---- stage y tile (128 threads) ----
  for (int i = tid; i < 16 * WIN; i += 128) {
    const int s = i / WIN;
    ybuf[s][i - s * WIN] = y[s0 * WIN + i];
  }

  // ---- per-H constants for OWN half: el = mtl*4+r -> H = (2w+mtl)*16 + 4g + r ----
  float wc_r[8], bc_r[8], lnwK[8], lnbK[8], dec_r[8];
#pragma unroll
  for (int mtl = 0; mtl < 2; ++mtl) {
    const int hb4 = (2 * w + mtl) * 16 + g * 4;
    const float4 wi = *(const float4*)&wcp[hb4];
    const float4 bi = *(const float4*)&bcp[hb4];
    const float4 lw = *(const float4*)&ln_w[hb4];
    const float4 lb = *(const float4*)&ln_b[hb4];
    const float4 dc = *(const float4*)&decp[hb4];
#pragma unroll
    for (int r = 0; r < 4; ++r) {
      wc_r[mtl * 4 + r] = (&wi.x)[r];
      bc_r[mtl * 4 + r] = (&bi.x)[r];
      lnwK[mtl * 4 + r] = (&lw.x)[r] * K2E;
      lnbK[mtl * 4 + r] = (&lb.x)[r] * K2E;
      dec_r[mtl * 4 + r] = (&dc.x)[r];
    }
  }

  // ---- centered W' A-fragments for own mt ----
  f16x4 wrec[2][4];
#pragma unroll
  for (int mtl = 0; mtl < 2; ++mtl)
#pragma unroll
    for (int kt = 0; kt < 4; ++kt)
      wrec[mtl][kt] = *(const f16x4*)&wrec16[(((2 * w + mtl) * 4 + kt) * 64 + l) * 4];

  __syncthreads();  // ybuf ready

  float hs[8] = {};
  f16x4 hb[4] = {};  // FULL h B-fragments (all 4 kt)
  const float inv64 = 1.0f / 64.0f;

  // ================= Phase 1: 100-step scan =================
  float xt = ybuf[c][0];
  for (int t = 0; t < WIN; ++t) {
    const float xtn = ybuf[c][t + 1];  // col 100 in-bounds (padded), unused at t=99
    f32x4 acc[2];
#pragma unroll
    for (int mtl = 0; mtl < 2; ++mtl) {
      f32x4 a;
#pragma unroll
      for (int r = 0; r < 4; ++r) a[r] = fmaf(xt, wc_r[mtl * 4 + r], bc_r[mtl * 4 + r]);
#pragma unroll
      for (int kt = 0; kt < 4; ++kt)
        a = __builtin_amdgcn_mfma_f32_16x16x16f16(wrec[mtl][kt], hb[kt], a, 0, 0, 0);
      acc[mtl] = a;
    }
    // variance partial over own 8 centered elems, reduce over g, exchange
    float q = acc[0][0] * acc[0][0];
    q = fmaf(acc[0][1], acc[0][1], q);
    q = fmaf(acc[0][2], acc[0][2], q);
    q = fmaf(acc[0][3], acc[0][3], q);
    q = fmaf(acc[1][0], acc[1][0], q);
    q = fmaf(acc[1][1], acc[1][1], q);
    q = fmaf(acc[1][2], acc[1][2], q);
    q = fmaf(acc[1][3], acc[1][3], q);
    q += __shfl_xor(q, 16);
    q += __shfl_xor(q, 32);
    qx[t & 1][w][l] = q;
    __syncthreads();  // A: publish q partial
    q += qx[t & 1][1 - w][l];
    const float rstd = rsq_fast(fmaf(q, inv64, LNEPS));
    f16x4 myfrag[2];
#pragma unroll
    for (int mtl = 0; mtl < 2; ++mtl) {
      float hn[4];
#pragma unroll
      for (int r = 0; r < 4; ++r) {
        const int e = mtl * 4 + r;
        const float u2 = fmaf(acc[mtl][r] * rstd, lnwK[e], lnbK[e]);  // 2u*log2e
        const float rr = rcp_fast(exp2_fast(u2) + 1.f);
        // DTC*tanh = 0.1*(1-2rr) = fma(-0.2, rr, 0.1)
        hn[r] = med3(fmaf(hs[e], dec_r[e], fmaf(-0.2f, rr, 0.1f)), -10.f, 10.f);
        hs[e] = hn[r];
      }
      myfrag[mtl] = pack4(hn[0], hn[1], hn[2], hn[3]);
      *(f16x4*)&hx[t & 1][w][mtl][l][0] = myfrag[mtl];
    }
    __syncthreads();  // B: publish h fragments
    hb[2 * w] = myfrag[0];
    hb[2 * w + 1] = myfrag[1];
    hb[2 * (1 - w)] = *(const f16x4*)&hx[t & 1][1 - w][0][l][0];
    hb[2 * (1 - w) + 1] = *(const f16x4*)&hx[t & 1][1 - w][1][l][0];
    xt = xtn;
  }

  // ================= Phase 2: x^T = Wx0 @ h^T + bx0 (own mt half) =================
  float xs[8];
  f16x4 xfr[4];
#pragma unroll
  for (int mtl = 0; mtl < 2; ++mtl) {
    const int mt = 2 * w + mtl;
    const float4 b4 = *(const float4*)&bx0[mt * 16 + 4 * g];
    f32x4 a = {b4.x, b4.y, b4.z, b4.w};
#pragma unroll
    for (int kt = 0; kt < 4; ++kt) {
      const float4 wv = *(const float4*)&Wx0[(mt * 16 + c) * HH + kt * 16 + 4 * g];
      a = __builtin_amdgcn_mfma_f32_16x16x16f16(pack4(wv.x, wv.y, wv.z, wv.w), hb[kt], a, 0, 0, 0);
    }
#pragma unroll
    for (int r = 0; r < 4; ++r) xs[mtl * 4 + r] = a[r];
    xfr[2 * w + mtl] = pack4(a[0], a[1], a[2], a[3]);
    *(f16x4*)&hx[0][w][mtl][l][0] = xfr[2 * w + mtl];
  }
  __syncthreads();  // exchange x fragments (buffer 0)
  xfr[2 * (1 - w)] = *(const f16x4*)&hx[0][1 - w][0][l][0];
  xfr[2 * (1 - w) + 1] = *(const f16x4*)&hx[0][1 - w][1][l][0];

  // ---- y^T B-fragments (wave-independent; t >= 100 zero, We padded in ws) ----
  f16x4 yfr[7];
#pragma unroll
  for (int kt = 0; kt < 7; ++kt) {
    const int t0 = kt * 16 + 4 * g;
    if (t0 + 3 < WIN) {
      yfr[kt] = pack4(ybuf[c][t0], ybuf[c][t0 + 1], ybuf[c][t0 + 2], ybuf[c][t0 + 3]);
    } else {
      yfr[kt] = pack4(0.f, 0.f, 0.f, 0.f);
    }
  }

  // ================= Phase 3: ISTA (own mt half, parity-buffered exchange) =================
  for (int k = 0; k < KITER; ++k) {
    f32x4 acc2[2];
#pragma unroll
    for (int mtl = 0; mtl < 2; ++mtl) {
      const int mt = 2 * w + mtl;
      const float4 be4 = *(const float4*)&be[k * AA + mt * 16 + 4 * g];
      f32x4 a = {be4.x, be4.y, be4.z, be4.w};
      const int rowe = (k * AA + mt * 16 + c) * 112;
#pragma unroll
      for (int kt = 0; kt < 7; ++kt) {
        const f16x4 wf = *(const f16x4*)&we16[rowe + kt * 16 + 4 * g];
        a = __builtin_amdgcn_mfma_f32_16x16x16f16(wf, yfr[kt], a, 0, 0, 0);
      }
      const int rowr = (k * AA + mt * 16 + c) * AA;
#pragma unroll
      for (int kt = 0; kt < 4; ++kt) {
        const f16x4 wf = *(const f16x4*)&wr16[rowr + kt * 16 + 4 * g];
        a = __builtin_amdgcn_mfma_f32_16x16x16f16(wf, xfr[kt], a, 0, 0, 0);
      }
      acc2[mtl] = a;
    }
#pragma unroll
    for (int mtl = 0; mtl < 2; ++mtl) {
      const int mt = 2 * w + mtl;
      const float4 lm4 = *(const float4*)&lamp[k * AA + mt * 16 + 4 * g];
      float xv[4];
#pragma unroll
      for (int r = 0; r < 4; ++r) {
        const float z = acc2[mtl][r];
        const float v = fmaxf(fabsf(z) - (&lm4.x)[r], 0.0f);
        xv[r] = copysignf(v, z);
        xs[mtl * 4 + r] = xv[r];
      }
      xfr[mt] = pack4(xv[0], xv[1], xv[2], xv[3]);
      *(f16x4*)&hx[(k + 1) & 1][w][mtl][l][0] = xfr[mt];
    }
    __syncthreads();  // publish x fragments for next iter
    xfr[2 * (1 - w)] = *(const f16x4*)&hx[(k + 1) & 1][1 - w][0][l][0];
    xfr[2 * (1 - w) + 1] = *(const f16x4*)&hx[(k + 1) & 1][1 - w][1][l][0];
  }

  // ================= Phase 4: outputs =================
  float* __restrict__ outp = out;               // power (B, 4)
  float* __restrict__ outx = out + NB * NAPPC;  // x (B, 64)
#pragma unroll
  for (int mtl = 0; mtl < 2; ++mtl) {
    float4 v;
#pragma unroll
    for (int r = 0; r < 4; ++r) (&v.x)[r] = xs[mtl * 4 + r];
    *(float4*)&outx[(s0 + c) * AA + (2 * w + mtl) * 16 + 4 * g] = v;
  }

  // head: partial over own 8 elems, reduce over g, combine across waves via LDS
  float P[4];
#pragma unroll
  for (int p = 0; p < NAPPC; ++p) {
    float acc = 0.f;
#pragma unroll
    for (int mtl = 0; mtl < 2; ++mtl) {
      const float4 hw = *(const float4*)&head_W[p * AA + (2 * w + mtl) * 16 + 4 * g];
#pragma unroll
      for (int r = 0; r < 4; ++r) acc = fmaf(xs[mtl * 4 + r], (&hw.x)[r], acc);
    }
    acc += __shfl_xor(acc, 16);
    acc += __shfl_xor(acc, 32);
    P[p] = acc;
  }
  if (g == 0) {
#pragma unroll
    for (int p = 0; p < NAPPC; ++p) px[w][p][c] = P[p];
  }
  __syncthreads();
  if (w == 0 && l < 16) {
    float4 pv;
#pragma unroll
    for (int p = 0; p < NAPPC; ++p)
      (&pv.x)[p] = px[0][p][l] + px[1][p][l] + head_b[p];
    *(float4*)&outp[(s0 + l) * NAPPC] = pv;
  }
}

extern "C" void kernel_launch(void* const* d_in, const int* in_sizes, int n_in,
                              void* d_out, int out_size, void* d_ws, size_t ws_size,
                              hipStream_t stream) {
  const float* y         = (const float*)d_in[0];
  const float* w_in      = (const float*)d_in[1];
  const float* b_in      = (const float*)d_in[2];
  const float* tau_param = (const float*)d_in[3];
  const float* W_rec     = (const float*)d_in[4];
  const float* ln_w      = (const float*)d_in[5];
  const float* ln_b      = (const float*)d_in[6];
  const float* Wx0       = (const float*)d_in[7];
  const float* bx0       = (const float*)d_in[8];
  const float* We        = (const float*)d_in[9];
  const float* be        = (const float*)d_in[10];
  const float* Wr        = (const float*)d_in[11];
  const float* thr       = (const float*)d_in[12];
  const float* head_W    = (const float*)d_in[13];
  const float* head_b    = (const float*)d_in[14];

  pinn_prep<<<dim3(90), dim3(256), 0, stream>>>(
      W_rec, w_in, b_in, tau_param, thr, We, Wr, (char*)d_ws);
  pinn_fused<<<dim3(NB / 16), dim3(128), 0, stream>>>(
      y, ln_w, ln_b, Wx0, bx0, be, head_W, head_b, (const char*)d_ws,
      (float*)d_out);
}

// Round 6
// 131.123 us; speedup vs baseline: 3.5529x; 3.5529x over previous
//
#include <hip/hip_runtime.h>

// Fully-fused PINN-LISTA, transposed-MFMA + prep prefold + 2-wave H-split.
// Block = 128 threads = 2 waves sharing one 16-sample tile; wave w owns
// output chunks mt in {2w, 2w+1}. ALL fragment arrays are indexed with
// compile-time constants via a per-wave slot permutation (slot 0,1 = own
// k-chunks, slot 2,3 = other wave's) -- the permutation is applied to the
// A-fragment ADDRESSES (runtime address math is fine) so no register array
// is ever runtime-indexed (avoids scratch demotion, cf. R5 regression).

#define NB 32768
#define WIN 100
#define HH 64
#define AA 64
#define KITER 8
#define NAPPC 4
#define DTC 0.1f
#define LNEPS 1e-5f
#define K2E 2.8853900817779268f  // 2*log2(e)

// d_ws byte offsets
#define WS_WREC 0        // f16 [4][4][64][4]   = 8192 B   ([mt*4+kchunk][lane][4])
#define WS_WE   8192     // f16 [8][64][112]    = 114688 B (K padded 100->112, zeros)
#define WS_WR   122880   // f16 [8][64][64]     = 65536 B
#define WS_WC   188416   // f32 [64]
#define WS_BC   188672   // f32 [64]
#define WS_DEC  188928   // f32 [64]
#define WS_LAM  189184   // f32 [8][64] -> ends 191232

typedef _Float16 f16x4 __attribute__((ext_vector_type(4)));
typedef __fp16 fp16x2 __attribute__((ext_vector_type(2)));
typedef float f32x4 __attribute__((ext_vector_type(4)));

union H4 { f16x4 v; fp16x2 h[2]; };

__device__ __forceinline__ float exp2_fast(float x) { return __builtin_amdgcn_exp2f(x); }
__device__ __forceinline__ float rcp_fast(float x) { return __builtin_amdgcn_rcpf(x); }
__device__ __forceinline__ float rsq_fast(float x) { return __builtin_amdgcn_rsqf(x); }
__device__ __forceinline__ float log2_fast(float x) { return __builtin_amdgcn_logf(x); }
__device__ __forceinline__ float med3(float x, float lo, float hi) {
  return __builtin_amdgcn_fmed3f(x, lo, hi);
}
__device__ __forceinline__ float softplus_fast(float x) {
  float ax = fabsf(x);
  float e = exp2_fast(-ax * 1.4426950408889634f);
  return fmaxf(x, 0.0f) + log2_fast(1.0f + e) * 0.6931471805599453f;
}
__device__ __forceinline__ f16x4 pack4(float a, float b, float c2, float d) {
  H4 t;
  t.h[0] = __builtin_amdgcn_cvt_pkrtz(a, b);
  t.h[1] = __builtin_amdgcn_cvt_pkrtz(c2, d);
  return t.v;
}

// ======================= prep kernel =======================
__global__ __launch_bounds__(256) void pinn_prep(
    const float* __restrict__ W_rec, const float* __restrict__ w_in,
    const float* __restrict__ b_in, const float* __restrict__ tau,
    const float* __restrict__ thr, const float* __restrict__ We,
    const float* __restrict__ Wr, char* __restrict__ ws) {
  _Float16* wrec16 = (_Float16*)(ws + WS_WREC);
  _Float16* we16 = (_Float16*)(ws + WS_WE);
  _Float16* wr16 = (_Float16*)(ws + WS_WR);
  float* wc = (float*)(ws + WS_WC);
  float* bc = (float*)(ws + WS_BC);
  float* dec = (float*)(ws + WS_DEC);
  float* lam = (float*)(ws + WS_LAM);
  const int tid = threadIdx.x, bid = blockIdx.x;
  if (bid == 0) {
    __shared__ float rm[64];
    if (tid < 64) {
      float s = 0.f;
      for (int m = 0; m < 64; ++m) s += W_rec[tid * 64 + m];
      rm[tid] = s * (1.f / 64.f);
    }
    __syncthreads();
    for (int idx = tid; idx < 4096; idx += 256) {
      const int j = idx & 3, l = (idx >> 2) & 63, kt = (idx >> 8) & 3, mt = idx >> 10;
      const int k_in = kt * 16 + ((l >> 4) << 2) + j, m = mt * 16 + (l & 15);
      wrec16[idx] = (_Float16)(W_rec[k_in * 64 + m] - rm[k_in]);
    }
    if (tid < 64) {
      float sw = 0.f, sb = 0.f;
      for (int i = 0; i < 64; ++i) { sw += w_in[i]; sb += b_in[i]; }
      wc[tid] = w_in[tid] - sw * (1.f / 64.f);
      bc[tid] = b_in[tid] - sb * (1.f / 64.f);
      dec[tid] = 1.f - DTC / softplus_fast(tau[tid]);
    }
    for (int i = tid; i < 512; i += 256) lam[i] = softplus_fast(thr[i]);
  } else {
    const int stride = (gridDim.x - 1) * 256;
    for (int i = (bid - 1) * 256 + tid; i < 57344 + 32768; i += stride) {
      if (i < 57344) {
        const int row = i / 112, t = i - row * 112;
        we16[i] = (t < WIN) ? (_Float16)We[row * WIN + t] : (_Float16)0.f;
      } else {
        const int j = i - 57344;
        wr16[j] = (_Float16)Wr[j];
      }
    }
  }
}

// ======================= main kernel =======================
__global__ __launch_bounds__(128, 4) void pinn_fused(
    const float* __restrict__ y, const float* __restrict__ ln_w,
    const float* __restrict__ ln_b, const float* __restrict__ Wx0,
    const float* __restrict__ bx0, const float* __restrict__ be,
    const float* __restrict__ head_W, const float* __restrict__ head_b,
    const char* __restrict__ ws, float* __restrict__ out) {
  __shared__ float ybuf[16][101];  // column reads: (c*101)%32 distinct -> conflict-free
  __shared__ __align__(16) _Float16 hx[2][2][2][64][4];  // [parity][wave][mtl][lane][4]
  __shared__ float qx[2][2][64];                          // [parity][wave][lane]
  __shared__ float px[2][4][16];                          // [wave][p][c] head partials

  const _Float16* wrec16 = (const _Float16*)(ws + WS_WREC);
  const _Float16* we16 = (const _Float16*)(ws + WS_WE);
  const _Float16* wr16 = (const _Float16*)(ws + WS_WR);
  const float* wcp = (const float*)(ws + WS_WC);
  const float* bcp = (const float*)(ws + WS_BC);
  const float* decp = (const float*)(ws + WS_DEC);
  const float* lamp = (const float*)(ws + WS_LAM);

  const int tid = threadIdx.x;
  const int w = tid >> 6;      // wave id: owns mt = 2w, 2w+1
  const int ow = 1 - w;        // other wave
  const int l = tid & 63;
  const int c = l & 15;        // sample (C col / B col / A row)
  const int g = l >> 4;        // lane group
  const int s0 = blockIdx.x * 16;

  // slot -> global k-chunk map (runtime values, used ONLY in address math)
  // slot 0,1 = own chunks; slot 2,3 = other wave's chunks
  int kmap[4];
  kmap[0] = 2 * w;
  kmap[1] = 2 * w + 1;
  kmap[2] = 2 * ow;
  kmap[3] = 2 * ow + 1;

  // ---- stage y tile (128 threads) ----
  for (int i = tid; i < 16 * WIN; i += 128) {
    const int s = i / WIN;
    ybuf[s][i - s * WIN] = y[s0 * WIN + i];
  }

  // ---- per-H constants for OWN half: e = mtl*4+r -> H = (2w+mtl)*16 + 4g + r ----
  float wc_r[8], bc_r[8], lnwK[8], lnbK[8], dec_r[8];
#pragma unroll
  for (int mtl = 0; mtl < 2; ++mtl) {
    const int hb4 = (2 * w + mtl) * 16 + g * 4;
    const float4 wi = *(const float4*)&wcp[hb4];
    const float4 bi = *(const float4*)&bcp[hb4];
    const float4 lw = *(const float4*)&ln_w[hb4];
    const float4 lb = *(const float4*)&ln_b[hb4];
    const float4 dc = *(const float4*)&decp[hb4];
#pragma unroll
    for (int r = 0; r < 4; ++r) {
      wc_r[mtl * 4 + r] = (&wi.x)[r];
      bc_r[mtl * 4 + r] = (&bi.x)[r];
      lnwK[mtl * 4 + r] = (&lw.x)[r] * K2E;
      lnbK[mtl * 4 + r] = (&lb.x)[r] * K2E;
      dec_r[mtl * 4 + r] = (&dc.x)[r];
    }
  }

  // ---- centered W' A-fragments for own mt, k-dim in SLOT order ----
  f16x4 wrec[2][4];
#pragma unroll
  for (int mtl = 0; mtl < 2; ++mtl)
#pragma unroll
    for (int s = 0; s < 4; ++s)
      wrec[mtl][s] = *(const f16x4*)&wrec16[(((2 * w + mtl) * 4 + kmap[s]) * 64 + l) * 4];

  __syncthreads();  // ybuf ready

  float hs[8] = {};
  f16x4 hb0 = {}, hb1 = {}, hb2 = {}, hb3 = {};  // h B-frags in slot order
  const float inv64 = 1.0f / 64.0f;

  // ================= Phase 1: 100-step scan =================
  float xt = ybuf[c][0];
  for (int t = 0; t < WIN; ++t) {
    const float xtn = ybuf[c][t + 1];  // col 100 in-bounds (padded), unused at t=99
    f32x4 acc[2];
#pragma unroll
    for (int mtl = 0; mtl < 2; ++mtl) {
      f32x4 a;
#pragma unroll
      for (int r = 0; r < 4; ++r) a[r] = fmaf(xt, wc_r[mtl * 4 + r], bc_r[mtl * 4 + r]);
      a = __builtin_amdgcn_mfma_f32_16x16x16f16(wrec[mtl][0], hb0, a, 0, 0, 0);
      a = __builtin_amdgcn_mfma_f32_16x16x16f16(wrec[mtl][1], hb1, a, 0, 0, 0);
      a = __builtin_amdgcn_mfma_f32_16x16x16f16(wrec[mtl][2], hb2, a, 0, 0, 0);
      a = __builtin_amdgcn_mfma_f32_16x16x16f16(wrec[mtl][3], hb3, a, 0, 0, 0);
      acc[mtl] = a;
    }
    // variance partial over own 8 centered elems, reduce over g, exchange
    float q = acc[0][0] * acc[0][0];
    q = fmaf(acc[0][1], acc[0][1], q);
    q = fmaf(acc[0][2], acc[0][2], q);
    q = fmaf(acc[0][3], acc[0][3], q);
    q = fmaf(acc[1][0], acc[1][0], q);
    q = fmaf(acc[1][1], acc[1][1], q);
    q = fmaf(acc[1][2], acc[1][2], q);
    q = fmaf(acc[1][3], acc[1][3], q);
    q += __shfl_xor(q, 16);
    q += __shfl_xor(q, 32);
    qx[t & 1][w][l] = q;
    __syncthreads();  // A: publish q partial
    q += qx[t & 1][ow][l];
    const float rstd = rsq_fast(fmaf(q, inv64, LNEPS));
    f16x4 my0, my1;
    {
      float hn[4];
#pragma unroll
      for (int r = 0; r < 4; ++r) {
        const float u2 = fmaf(acc[0][r] * rstd, lnwK[r], lnbK[r]);  // 2u*log2e
        const float rr = rcp_fast(exp2_fast(u2) + 1.f);
        hn[r] = med3(fmaf(hs[r], dec_r[r], fmaf(-0.2f, rr, 0.1f)), -10.f, 10.f);
        hs[r] = hn[r];
      }
      my0 = pack4(hn[0], hn[1], hn[2], hn[3]);
#pragma unroll
      for (int r = 0; r < 4; ++r) {
        const float u2 = fmaf(acc[1][r] * rstd, lnwK[4 + r], lnbK[4 + r]);
        const float rr = rcp_fast(exp2_fast(u2) + 1.f);
        hn[r] = med3(fmaf(hs[4 + r], dec_r[4 + r], fmaf(-0.2f, rr, 0.1f)), -10.f, 10.f);
        hs[4 + r] = hn[r];
      }
      my1 = pack4(hn[0], hn[1], hn[2], hn[3]);
    }
    *(f16x4*)&hx[t & 1][w][0][l][0] = my0;
    *(f16x4*)&hx[t & 1][w][1][l][0] = my1;
    __syncthreads();  // B: publish h fragments
    hb0 = my0;
    hb1 = my1;
    hb2 = *(const f16x4*)&hx[t & 1][ow][0][l][0];
    hb3 = *(const f16x4*)&hx[t & 1][ow][1][l][0];
    xt = xtn;
  }

  // ================= Phase 2: x^T = Wx0 @ h^T + bx0 (own mt half) =================
  float xs[8];
  f16x4 xf0, xf1, xf2, xf3;  // slot order
#pragma unroll
  for (int mtl = 0; mtl < 2; ++mtl) {
    const int mt = 2 * w + mtl;
    const float4 b4 = *(const float4*)&bx0[mt * 16 + 4 * g];
    f32x4 a = {b4.x, b4.y, b4.z, b4.w};
    {
      const float4 wv = *(const float4*)&Wx0[(mt * 16 + c) * HH + kmap[0] * 16 + 4 * g];
      a = __builtin_amdgcn_mfma_f32_16x16x16f16(pack4(wv.x, wv.y, wv.z, wv.w), hb0, a, 0, 0, 0);
    }
    {
      const float4 wv = *(const float4*)&Wx0[(mt * 16 + c) * HH + kmap[1] * 16 + 4 * g];
      a = __builtin_amdgcn_mfma_f32_16x16x16f16(pack4(wv.x, wv.y, wv.z, wv.w), hb1, a, 0, 0, 0);
    }
    {
      const float4 wv = *(const float4*)&Wx0[(mt * 16 + c) * HH + kmap[2] * 16 + 4 * g];
      a = __builtin_amdgcn_mfma_f32_16x16x16f16(pack4(wv.x, wv.y, wv.z, wv.w), hb2, a, 0, 0, 0);
    }
    {
      const float4 wv = *(const float4*)&Wx0[(mt * 16 + c) * HH + kmap[3] * 16 + 4 * g];
      a = __builtin_amdgcn_mfma_f32_16x16x16f16(pack4(wv.x, wv.y, wv.z, wv.w), hb3, a, 0, 0, 0);
    }
#pragma unroll
    for (int r = 0; r < 4; ++r) xs[mtl * 4 + r] = a[r];
    const f16x4 xf = pack4(a[0], a[1], a[2], a[3]);
    if (mtl == 0) xf0 = xf; else xf1 = xf;
    *(f16x4*)&hx[0][w][mtl][l][0] = xf;
  }
  __syncthreads();  // exchange x fragments (buffer 0)
  xf2 = *(const f16x4*)&hx[0][ow][0][l][0];
  xf3 = *(const f16x4*)&hx[0][ow][1][l][0];

  // ---- y^T B-fragments (wave-independent; t >= 100 zero, We padded in ws) ----
  f16x4 yfr[7];
#pragma unroll
  for (int kt = 0; kt < 7; ++kt) {
    const int t0 = kt * 16 + 4 * g;
    if (t0 + 3 < WIN) {
      yfr[kt] = pack4(ybuf[c][t0], ybuf[c][t0 + 1], ybuf[c][t0 + 2], ybuf[c][t0 + 3]);
    } else {
      yfr[kt] = pack4(0.f, 0.f, 0.f, 0.f);
    }
  }

  // ================= Phase 3: ISTA (own mt half, parity-buffered exchange) =================
  for (int k = 0; k < KITER; ++k) {
    f32x4 acc2[2];
#pragma unroll
    for (int mtl = 0; mtl < 2; ++mtl) {
      const int mt = 2 * w + mtl;
      const float4 be4 = *(const float4*)&be[k * AA + mt * 16 + 4 * g];
      f32x4 a = {be4.x, be4.y, be4.z, be4.w};
      const int rowe = (k * AA + mt * 16 + c) * 112;
#pragma unroll
      for (int kt = 0; kt < 7; ++kt) {
        const f16x4 wf = *(const f16x4*)&we16[rowe + kt * 16 + 4 * g];
        a = __builtin_amdgcn_mfma_f32_16x16x16f16(wf, yfr[kt], a, 0, 0, 0);
      }
      const int rowr = (k * AA + mt * 16 + c) * AA;
      {
        const f16x4 wf = *(const f16x4*)&wr16[rowr + kmap[0] * 16 + 4 * g];
        a = __builtin_amdgcn_mfma_f32_16x16x16f16(wf, xf0, a, 0, 0, 0);
      }
      {
        const f16x4 wf = *(const f16x4*)&wr16[rowr + kmap[1] * 16 + 4 * g];
        a = __builtin_amdgcn_mfma_f32_16x16x16f16(wf, xf1, a, 0, 0, 0);
      }
      {
        const f16x4 wf = *(const f16x4*)&wr16[rowr + kmap[2] * 16 + 4 * g];
        a = __builtin_amdgcn_mfma_f32_16x16x16f16(wf, xf2, a, 0, 0, 0);
      }
      {
        const f16x4 wf = *(const f16x4*)&wr16[rowr + kmap[3] * 16 + 4 * g];
        a = __builtin_amdgcn_mfma_f32_16x16x16f16(wf, xf3, a, 0, 0, 0);
      }
      acc2[mtl] = a;
    }
#pragma unroll
    for (int mtl = 0; mtl < 2; ++mtl) {
      const int mt = 2 * w + mtl;
      const float4 lm4 = *(const float4*)&lamp[k * AA + mt * 16 + 4 * g];
      float xv[4];
#pragma unroll
      for (int r = 0; r < 4; ++r) {
        const float z = acc2[mtl][r];
        const float v = fmaxf(fabsf(z) - (&lm4.x)[r], 0.0f);
        xv[r] = copysignf(v, z);
        xs[mtl * 4 + r] = xv[r];
      }
      const f16x4 xf = pack4(xv[0], xv[1], xv[2], xv[3]);
      if (mtl == 0) xf0 = xf; else xf1 = xf;
      *(f16x4*)&hx[(k + 1) & 1][w][mtl][l][0] = xf;
    }
    __syncthreads();  // publish x fragments for next iter
    xf2 = *(const f16x4*)&hx[(k + 1) & 1][ow][0][l][0];
    xf3 = *(const f16x4*)&hx[(k + 1) & 1][ow][1][l][0];
  }

  // ================= Phase 4: outputs =================
  float* __restrict__ outp = out;               // power (B, 4)
  float* __restrict__ outx = out + NB * NAPPC;  // x (B, 64)
#pragma unroll
  for (int mtl = 0; mtl < 2; ++mtl) {
    float4 v;
#pragma unroll
    for (int r = 0; r < 4; ++r) (&v.x)[r] = xs[mtl * 4 + r];
    *(float4*)&outx[(s0 + c) * AA + (2 * w + mtl) * 16 + 4 * g] = v;
  }

  // head: partial over own 8 elems, reduce over g, combine across waves via LDS
  float P[4];
#pragma unroll
  for (int p = 0; p < NAPPC; ++p) {
    float acc = 0.f;
#pragma unroll
    for (int mtl = 0; mtl < 2; ++mtl) {
      const float4 hw = *(const float4*)&head_W[p * AA + (2 * w + mtl) * 16 + 4 * g];
#pragma unroll
      for (int r = 0; r < 4; ++r) acc = fmaf(xs[mtl * 4 + r], (&hw.x)[r], acc);
    }
    acc += __shfl_xor(acc, 16);
    acc += __shfl_xor(acc, 32);
    P[p] = acc;
  }
  if (g == 0) {
#pragma unroll
    for (int p = 0; p < NAPPC; ++p) px[w][p][c] = P[p];
  }
  __syncthreads();
  if (w == 0 && l < 16) {
    float4 pv;
#pragma unroll
    for (int p = 0; p < NAPPC; ++p)
      (&pv.x)[p] = px[0][p][l] + px[1][p][l] + head_b[p];
    *(float4*)&outp[(s0 + l) * NAPPC] = pv;
  }
}

extern "C" void kernel_launch(void* const* d_in, const int* in_sizes, int n_in,
                              void* d_out, int out_size, void* d_ws, size_t ws_size,
                              hipStream_t stream) {
  const float* y         = (const float*)d_in[0];
  const float* w_in      = (const float*)d_in[1];
  const float* b_in      = (const float*)d_in[2];
  const float* tau_param = (const float*)d_in[3];
  const float* W_rec     = (const float*)d_in[4];
  const float* ln_w      = (const float*)d_in[5];
  const float* ln_b      = (const float*)d_in[6];
  const float* Wx0       = (const float*)d_in[7];
  const float* bx0       = (const float*)d_in[8];
  const float* We        = (const float*)d_in[9];
  const float* be        = (const float*)d_in[10];
  const float* Wr        = (const float*)d_in[11];
  const float* thr       = (const float*)d_in[12];
  const float* head_W    = (const float*)d_in[13];
  const float* head_b    = (const float*)d_in[14];

  pinn_prep<<<dim3(90), dim3(256), 0, stream>>>(
      W_rec, w_in, b_in, tau_param, thr, We, Wr, (char*)d_ws);
  pinn_fused<<<dim3(NB / 16), dim3(128), 0, stream>>>(
      y, ln_w, ln_b, Wx0, bx0, be, head_W, head_b, (const char*)d_ws,
      (float*)d_out);
}